// Round 8
// baseline (192.967 us; speedup 1.0000x reference)
//
#include <hip/hip_runtime.h>
#include <hip/hip_fp16.h>

// 2-layer single-head GATConv, fp32 in/out, MI355X.
// N=50000 nodes, E=800000 edges, IN=128, HID=64, OUT=32.
//
// Round 7 -> 8:
//  (a) k_bin was occupancy-starved (98 blocks x 1024 thr -> <=98/256 CUs) and
//      LDS-atomic contended. Now 782 blocks x 256 thr x 4 edges (~3 blocks/CU,
//      8x less per-block histogram contention).
//  (b) k_epi1 fused into k_agg1 (k_agg1f): after slot-reduction the wave
//      relu's its 64-ch row into LDS and does the 64x32 GEMM2 + ls2/ld2
//      scores in-wave (k-split across half-waves). Deletes acc1 (25.6 MB
//      round-trip) and one launch. h2h/ls2/ld2 no longer alias layer-1
//      arrays (producer+consumer overlap inside one kernel now).

#define N_NODES 50000
#define N_EDGES 800000
#define SLOPE 0.2f
#define NBUCK 196           // ceil(50000/256) buckets of 256 dst nodes
#define CAP 4608            // staging capacity per bucket (mean ~4082, sigma ~64)

typedef _Float16 half4 __attribute__((ext_vector_type(4)));

// ---------------------------------------------------------------------------
__global__ __launch_bounds__(256) void k_zerobins(int* __restrict__ binctr)
{
    if (threadIdx.x < NBUCK) binctr[threadIdx.x] = 0;
}

// Stage edges into per-bucket regions. 782 blocks x 256 thr x 4 edges.
// Packed: s | ((d&255)<<16); bucket d>>8 is implicit in the staging slot.
__global__ __launch_bounds__(256) void k_bin(
    const int* __restrict__ src, const int* __restrict__ dst,
    int* __restrict__ binctr, int* __restrict__ stg)
{
    __shared__ int hist[NBUCK];
    __shared__ int gb[NBUCK];
    const int t = threadIdx.x;
    if (t < NBUCK) hist[t] = 0;
    __syncthreads();

    const int base = blockIdx.x * 1024;
    int mp[4], mb[4], mr[4];
    int n = 0;
    #pragma unroll
    for (int k = 0; k < 4; ++k) {
        int e = base + t + k * 256;
        if (e < N_EDGES) {
            int s = src[e], d = dst[e];
            int b = d >> 8;
            mp[n] = s | ((d & 255) << 16);         // s fits in 16 bits
            mb[n] = b;
            mr[n] = atomicAdd(&hist[b], 1);        // rank within block-bucket
            ++n;
        }
    }
    __syncthreads();
    if (t < NBUCK) gb[t] = atomicAdd(&binctr[t], hist[t]);  // reserve range
    __syncthreads();
    for (int i = 0; i < n; ++i)
        stg[mb[i] * CAP + gb[mb[i]] + mr[i]] = mp[i];
}

// Exclusive scan of 196 bucket counts -> bucket_base.
__global__ __launch_bounds__(256) void k_btot(
    const int* __restrict__ binctr, int* __restrict__ bucket_base)
{
    __shared__ int tmp[256];
    const int t = threadIdx.x;
    int v = (t < NBUCK) ? binctr[t] : 0;
    tmp[t] = v;
    __syncthreads();
    #pragma unroll
    for (int off = 1; off < 256; off <<= 1) {
        int u = (t >= off) ? tmp[t - off] : 0;
        __syncthreads();
        tmp[t] += u;
        __syncthreads();
    }
    if (t < NBUCK) bucket_base[t] = tmp[t] - v;
}

// One block per bucket: counting-sort its 256 dst nodes in LDS, write
// contiguous csr_src slice + row_start for its nodes.
__global__ __launch_bounds__(1024) void k_sort(
    const int* __restrict__ stg,
    const int* __restrict__ binctr, const int* __restrict__ bucket_base,
    int* __restrict__ row_start, int* __restrict__ csr_src)
{
    __shared__ int cnt[256];
    __shared__ int off[256];
    const int b = blockIdx.x, t = threadIdx.x;
    const int n = binctr[b];
    const int sbase = b * CAP;
    const int obase = bucket_base[b];

    if (t < 256) cnt[t] = 0;
    __syncthreads();

    int mv[5], mk[5], mr[5];
    int c = 0;
    for (int i = t; i < n; i += 1024) {
        int v = stg[sbase + i];
        int k = v >> 16;                 // dst & 255
        mv[c] = v & 0xFFFF;              // src
        mk[c] = k;
        mr[c] = atomicAdd(&cnt[k], 1);
        ++c;
    }
    __syncthreads();

    if (t < 256) off[t] = cnt[t];
    __syncthreads();
    #pragma unroll
    for (int o = 1; o < 256; o <<= 1) {
        int u = (t < 256 && t >= o) ? off[t - o] : 0;
        __syncthreads();
        if (t < 256) off[t] += u;
        __syncthreads();
    }
    // off = inclusive scan; exclusive prefix = off[k] - cnt[k]

    if (t < 256) {
        int node = b * 256 + t;
        if (node < N_NODES) row_start[node] = obase + off[t] - cnt[t];
    }
    if (b == NBUCK - 1 && t == 0) row_start[N_NODES] = N_EDGES;

    for (int i = 0; i < c; ++i)
        csr_src[obase + off[mk[i]] - cnt[mk[i]] + mr[i]] = mv[i];
}

// ---------------------------------------------------------------------------
// GEMM1: h1 = x @ W1  (50000x128 @ 128x64) -> fp16 rows; fused ls1/ld1 (fp32).
__global__ __launch_bounds__(256) void k_gemm1(
    const float* __restrict__ x, const float* __restrict__ W1,
    const float* __restrict__ a_src, const float* __restrict__ a_dst,
    _Float16* __restrict__ h1h, float* __restrict__ ls, float* __restrict__ ld)
{
    __shared__ float As[64][128];   // 32 KB
    __shared__ float Bs[128][64];   // 32 KB
    const int tid = threadIdx.x;
    const int m0 = blockIdx.x * 64;

    {   // W1 (128x64 = 2048 float4) -> Bs
        const float4* Wv = (const float4*)W1;
        float4* Bv = (float4*)&Bs[0][0];
        #pragma unroll
        for (int i = 0; i < 8; ++i) Bv[tid + i * 256] = Wv[tid + i * 256];
    }
    {   // x tile (64x128) -> As, coalesced float4, zero-pad past N
        const float4* Xv = (const float4*)x;
        #pragma unroll
        for (int i = 0; i < 8; ++i) {
            int idx = tid + i * 256;
            int r = idx >> 5, kq = idx & 31;        // 32 float4 per row
            float4 v = make_float4(0.f, 0.f, 0.f, 0.f);
            if (m0 + r < N_NODES) v = Xv[(size_t)(m0 + r) * 32 + kq];
            ((float4*)&As[r][0])[kq] = v;
        }
    }
    __syncthreads();

    const int tx = tid & 15, ty = tid >> 4;
    const int c0 = tx * 4, r0 = ty * 4;
    float acc[4][4] = {};
    for (int k = 0; k < 128; k += 4) {
        float a_s[4][4];
        #pragma unroll
        for (int i = 0; i < 4; ++i) {
            float4 av = *(const float4*)&As[r0 + i][k];
            a_s[i][0] = av.x; a_s[i][1] = av.y; a_s[i][2] = av.z; a_s[i][3] = av.w;
        }
        #pragma unroll
        for (int kk = 0; kk < 4; ++kk) {
            float4 b = *(const float4*)&Bs[k + kk][c0];
            #pragma unroll
            for (int i = 0; i < 4; ++i) {
                acc[i][0] += a_s[i][kk] * b.x;
                acc[i][1] += a_s[i][kk] * b.y;
                acc[i][2] += a_s[i][kk] * b.z;
                acc[i][3] += a_s[i][kk] * b.w;
            }
        }
    }

    float as4[4], ad4[4];
    #pragma unroll
    for (int j = 0; j < 4; ++j) { as4[j] = a_src[c0 + j]; ad4[j] = a_dst[c0 + j]; }

    #pragma unroll
    for (int i = 0; i < 4; ++i) {
        int row = m0 + r0 + i;
        float pls = acc[i][0]*as4[0] + acc[i][1]*as4[1] + acc[i][2]*as4[2] + acc[i][3]*as4[3];
        float pld = acc[i][0]*ad4[0] + acc[i][1]*ad4[1] + acc[i][2]*ad4[2] + acc[i][3]*ad4[3];
        #pragma unroll
        for (int off = 1; off < 16; off <<= 1) {
            pls += __shfl_xor(pls, off, 64);
            pld += __shfl_xor(pld, off, 64);
        }
        if (row < N_NODES) {
            half4 hv;
            hv.x = (_Float16)acc[i][0]; hv.y = (_Float16)acc[i][1];
            hv.z = (_Float16)acc[i][2]; hv.w = (_Float16)acc[i][3];
            ((half4*)&h1h[(size_t)row * 64])[tx] = hv;
            if (tx == 0) { ls[row] = pls; ld[row] = pld; }
        }
    }
}

// ---------------------------------------------------------------------------
// Fused aggregate layer 1 + epilogue + GEMM2 + layer-2 scores.
// One wave per dst node. Gather phase: lane = (eslot, c4) as before.
// Then: row = relu(acc/sw + b1) -> LDS; h2 = row @ W2 in-wave (k-split
// across half-waves); ls2/ld2 fused; h2 written as fp16.
__global__ __launch_bounds__(256) void k_agg1f(
    const int* __restrict__ csr_src, const int* __restrict__ row_start,
    const float* __restrict__ ls, const float* __restrict__ ld,
    const _Float16* __restrict__ h1h, const float* __restrict__ b1,
    const float* __restrict__ W2,
    const float* __restrict__ a_src2, const float* __restrict__ a_dst2,
    _Float16* __restrict__ h2h, float* __restrict__ ls2, float* __restrict__ ld2)
{
    __shared__ float W2s[64][32];   // 8 KB
    __shared__ float rows[4][64];   // 1 KB (one relu'd row per wave)
    const int tid = threadIdx.x;
    {   // W2 (64x32 = 512 float4) -> LDS
        const float4* Wv = (const float4*)W2;
        float4* Ws = (float4*)&W2s[0][0];
        Ws[tid] = Wv[tid];
        Ws[tid + 256] = Wv[tid + 256];
    }
    __syncthreads();

    const int wid = tid >> 6;
    const int node = blockIdx.x * 4 + wid;  // 12500*4 == N_NODES
    const int lane = tid & 63;
    const int c4 = lane & 15, eslot = lane >> 4;
    const int beg = row_start[node], end = row_start[node + 1];
    const float ldv = ld[node];
    const half4* H = (const half4*)h1h;

    float4 acc = make_float4(0.f, 0.f, 0.f, 0.f);
    float sw = 0.f;
    for (int base = beg; base < end; base += 64) {
        const int cnt = min(64, end - base);
        int s = 0;
        float w = 0.f;
        if (lane < cnt) {
            s = csr_src[base + lane];              // coalesced
            float l = ls[s] + ldv;                 // one exp per EDGE
            l = l > 0.f ? l : SLOPE * l;
            w = __expf(l);
        }
        float wsum = w;                            // denominator via butterfly
        #pragma unroll
        for (int off = 1; off < 64; off <<= 1) wsum += __shfl_xor(wsum, off, 64);
        sw += wsum;

        int j = 0;                                 // 8 edges per iter (2/slot)
        for (; j + 8 <= cnt; j += 8) {
            int   s0 = __shfl(s, j + eslot, 64);
            int   s1 = __shfl(s, j + 4 + eslot, 64);
            float w0 = __shfl(w, j + eslot, 64);
            float w1 = __shfl(w, j + 4 + eslot, 64);
            half4 g0 = H[(size_t)s0 * 16 + c4];
            half4 g1 = H[(size_t)s1 * 16 + c4];
            acc.x += w0 * (float)g0.x; acc.y += w0 * (float)g0.y;
            acc.z += w0 * (float)g0.z; acc.w += w0 * (float)g0.w;
            acc.x += w1 * (float)g1.x; acc.y += w1 * (float)g1.y;
            acc.z += w1 * (float)g1.z; acc.w += w1 * (float)g1.w;
        }
        for (; j < cnt; j += 4) {                  // tail: invalid slots have w=0
            int   sj = __shfl(s, j + eslot, 64);
            float wj = __shfl(w, j + eslot, 64);
            half4 g = H[(size_t)sj * 16 + c4];
            acc.x += wj * (float)g.x; acc.y += wj * (float)g.y;
            acc.z += wj * (float)g.z; acc.w += wj * (float)g.w;
        }
    }
    // reduce across the 4 edge slots (xor bits 4,5)
    #pragma unroll
    for (int off = 16; off < 64; off <<= 1) {
        acc.x += __shfl_xor(acc.x, off, 64);
        acc.y += __shfl_xor(acc.y, off, 64);
        acc.z += __shfl_xor(acc.z, off, 64);
        acc.w += __shfl_xor(acc.w, off, 64);
    }
    if (eslot == 0) {
        float inv = sw > 0.f ? 1.f / sw : 0.f;
        float4 bb = ((const float4*)b1)[c4];
        float4 r;
        r.x = fmaxf(acc.x * inv + bb.x, 0.f);
        r.y = fmaxf(acc.y * inv + bb.y, 0.f);
        r.z = fmaxf(acc.z * inv + bb.z, 0.f);
        r.w = fmaxf(acc.w * inv + bb.w, 0.f);
        ((float4*)&rows[wid][0])[c4] = r;
    }
    __syncthreads();   // rows visible (each wave reads only its own row)

    // GEMM2 in-wave: channel ch = lane&31, k-split across half-waves.
    const int ch = lane & 31;
    const int kh = (lane >> 5) * 32;
    const float* row = &rows[wid][0];
    float hv = 0.f;
    #pragma unroll
    for (int k = 0; k < 32; ++k)
        hv += row[kh + k] * W2s[kh + k][ch];       // LDS broadcast + stride-1
    hv += __shfl_xor(hv, 32, 64);                  // combine k-halves

    float pls = hv * a_src2[ch];
    float pld = hv * a_dst2[ch];
    #pragma unroll
    for (int off = 1; off < 32; off <<= 1) {       // reduce over 32 channels
        pls += __shfl_xor(pls, off, 64);
        pld += __shfl_xor(pld, off, 64);
    }
    if (lane < 32) h2h[(size_t)node * 32 + ch] = (_Float16)hv;
    if (lane == 0) { ls2[node] = pls; ld2[node] = pld; }
}

// ---------------------------------------------------------------------------
// Aggregate layer 2 (C=32): one 32-lane group per dst node.
// c4 = grp&7 (8 half4 channel groups, 64 B/row), eslot = grp>>3 (4 slots).
__global__ __launch_bounds__(256) void k_agg2(
    const int* __restrict__ csr_src, const int* __restrict__ row_start,
    const float* __restrict__ ls, const float* __restrict__ ld,
    const _Float16* __restrict__ h2h, const float* __restrict__ b2,
    float* __restrict__ out)
{
    const int idx = blockIdx.x * 256 + threadIdx.x;   // 6250*256 == N*32
    const int node = idx >> 5;
    const int grp = idx & 31;
    const int c4 = grp & 7, eslot = grp >> 3;
    const int beg = row_start[node], end = row_start[node + 1];
    const float ldv = ld[node];
    const half4* H = (const half4*)h2h;

    float4 acc = make_float4(0.f, 0.f, 0.f, 0.f);
    float sw = 0.f;
    for (int base = beg; base < end; base += 32) {
        const int cnt = min(32, end - base);
        int s = 0;
        float w = 0.f;
        if (grp < cnt) {
            s = csr_src[base + grp];
            float l = ls[s] + ldv;
            l = l > 0.f ? l : SLOPE * l;
            w = __expf(l);
        }
        float wsum = w;
        #pragma unroll
        for (int off = 1; off < 32; off <<= 1) wsum += __shfl_xor(wsum, off, 32);
        sw += wsum;

        int j = 0;
        for (; j + 8 <= cnt; j += 8) {
            int   s0 = __shfl(s, j + eslot, 32);
            int   s1 = __shfl(s, j + 4 + eslot, 32);
            float w0 = __shfl(w, j + eslot, 32);
            float w1 = __shfl(w, j + 4 + eslot, 32);
            half4 g0 = H[(size_t)s0 * 8 + c4];
            half4 g1 = H[(size_t)s1 * 8 + c4];
            acc.x += w0 * (float)g0.x; acc.y += w0 * (float)g0.y;
            acc.z += w0 * (float)g0.z; acc.w += w0 * (float)g0.w;
            acc.x += w1 * (float)g1.x; acc.y += w1 * (float)g1.y;
            acc.z += w1 * (float)g1.z; acc.w += w1 * (float)g1.w;
        }
        for (; j < cnt; j += 4) {
            int   sj = __shfl(s, j + eslot, 32);
            float wj = __shfl(w, j + eslot, 32);
            half4 g = H[(size_t)sj * 8 + c4];
            acc.x += wj * (float)g.x; acc.y += wj * (float)g.y;
            acc.z += wj * (float)g.z; acc.w += wj * (float)g.w;
        }
    }
    // reduce across the 4 edge slots (xor bits 3,4 of grp)
    #pragma unroll
    for (int off = 8; off < 32; off <<= 1) {
        acc.x += __shfl_xor(acc.x, off, 32);
        acc.y += __shfl_xor(acc.y, off, 32);
        acc.z += __shfl_xor(acc.z, off, 32);
        acc.w += __shfl_xor(acc.w, off, 32);
    }
    if (eslot == 0) {
        float inv = sw > 0.f ? 1.f / sw : 0.f;
        float4 bb = ((const float4*)b2)[c4];
        ((float4*)&out[(size_t)node * 32])[c4] =
            make_float4(acc.x * inv + bb.x, acc.y * inv + bb.y,
                        acc.z * inv + bb.z, acc.w * inv + bb.w);
    }
}

// ---------------------------------------------------------------------------
extern "C" void kernel_launch(void* const* d_in, const int* in_sizes, int n_in,
                              void* d_out, int out_size, void* d_ws, size_t ws_size,
                              hipStream_t stream)
{
    const float* x      = (const float*)d_in[0];
    const int*   ei     = (const int*)  d_in[1];
    const float* W1     = (const float*)d_in[2];
    const float* a_src1 = (const float*)d_in[3];
    const float* a_dst1 = (const float*)d_in[4];
    const float* b1     = (const float*)d_in[5];
    const float* W2     = (const float*)d_in[6];
    const float* a_src2 = (const float*)d_in[7];
    const float* a_dst2 = (const float*)d_in[8];
    const float* b2     = (const float*)d_in[9];
    const int* src = ei;
    const int* dst = ei + N_EDGES;
    float* out = (float*)d_out;

    // workspace layout (4B words), total ~3.45M words = 13.8 MB.
    // stg (903,168 ints) aliases h1h (1.6M words): CSR build precedes gemm1.
    // h2h/ls2/ld2 are SEPARATE from h1h/ls1/ld1 (k_agg1f reads layer-1 data
    // while writing layer-2 data).
    float* ws   = (float*)d_ws;
    _Float16* h1h = (_Float16*)ws;           // words 0 .. 1,600,000
    _Float16* h2h = (_Float16*)(ws + 1600000); // 800,000 words (50000x32 fp16)
    float* ls1  = ws + 2400000;              // 50,000 f
    float* ld1  = ws + 2450000;              // 50,000 f
    float* ls2  = ws + 2500000;              // 50,000 f
    float* ld2  = ws + 2550000;              // 50,000 f
    int* row_start   = (int*)(ws + 2600000); // 50,001 i (pad to 50,016)
    int* csr_src     = (int*)(ws + 2650016); // 800,000 i
    int* binctr      = (int*)(ws + 3450016); // 196 i (pad 256)
    int* bucket_base = (int*)(ws + 3450272); // 196 i (pad 256)
    int* stg = (int*)ws;                     // aliases h1h region

    // CSR build (dst-sorted, reused by both layers)
    k_zerobins<<<1,   256,  0, stream>>>(binctr);
    k_bin     <<<782, 256,  0, stream>>>(src, dst, binctr, stg);
    k_btot    <<<1,   256,  0, stream>>>(binctr, bucket_base);
    k_sort    <<<NBUCK, 1024, 0, stream>>>(stg, binctr, bucket_base,
                                           row_start, csr_src);

    // layer 1 (gemm) -> fused agg1+epilogue+gemm2 -> layer-2 aggregate
    k_gemm1<<<782,   256, 0, stream>>>(x, W1, a_src1, a_dst1, h1h, ls1, ld1);
    k_agg1f<<<12500, 256, 0, stream>>>(csr_src, row_start, ls1, ld1, h1h, b1,
                                       W2, a_src2, a_dst2, h2h, ls2, ld2);
    k_agg2 <<<6250,  256, 0, stream>>>(csr_src, row_start, ls2, ld2, h2h, b2, out);
}

// Round 9
// 181.543 us; speedup vs baseline: 1.0629x; 1.0629x over previous
//
#include <hip/hip_runtime.h>
#include <hip/hip_fp16.h>

// 2-layer single-head GATConv, fp32 in/out, MI355X.
// N=50000 nodes, E=800000 edges, IN=128, HID=64, OUT=32.
//
// Round 8 -> 9: round 8 (k_bin 782x256 + epi1-fusion w/ __syncthreads)
// REGRESSED 181.5->193: small bin blocks destroyed staging write density
// (~5-entry runs), and the fusion barrier coupled 4 Poisson-degree waves.
// This round: exact round-7 structure, ONE change: k_bin at 196 blocks x
// 1024 thr x 4 edges (2x CU coverage, runs stay ~21 entries = line-dense).

#define N_NODES 50000
#define N_EDGES 800000
#define SLOPE 0.2f
#define NBUCK 196           // ceil(50000/256) buckets of 256 dst nodes
#define CAP 4608            // staging capacity per bucket (mean ~4082, sigma ~64)

typedef _Float16 half4 __attribute__((ext_vector_type(4)));

// ---------------------------------------------------------------------------
__global__ __launch_bounds__(256) void k_zerobins(int* __restrict__ binctr)
{
    if (threadIdx.x < NBUCK) binctr[threadIdx.x] = 0;
}

// Stage edges into per-bucket regions. 196 blocks x 1024 thr x 4 edges.
// Packed: s | ((d&255)<<16); bucket d>>8 is implicit in the staging slot.
__global__ __launch_bounds__(1024) void k_bin(
    const int* __restrict__ src, const int* __restrict__ dst,
    int* __restrict__ binctr, int* __restrict__ stg)
{
    __shared__ int hist[NBUCK];
    __shared__ int gb[NBUCK];
    const int t = threadIdx.x;
    if (t < NBUCK) hist[t] = 0;
    __syncthreads();

    const int base = blockIdx.x * 4096;
    int mp[4], mb[4], mr[4];
    int n = 0;
    #pragma unroll
    for (int k = 0; k < 4; ++k) {
        int e = base + t + k * 1024;
        if (e < N_EDGES) {
            int s = src[e], d = dst[e];
            int b = d >> 8;
            mp[n] = s | ((d & 255) << 16);         // s fits in 16 bits
            mb[n] = b;
            mr[n] = atomicAdd(&hist[b], 1);        // rank within block-bucket
            ++n;
        }
    }
    __syncthreads();
    if (t < NBUCK) gb[t] = atomicAdd(&binctr[t], hist[t]);  // reserve range
    __syncthreads();
    for (int i = 0; i < n; ++i)
        stg[mb[i] * CAP + gb[mb[i]] + mr[i]] = mp[i];
}

// Exclusive scan of 196 bucket counts -> bucket_base.
__global__ __launch_bounds__(256) void k_btot(
    const int* __restrict__ binctr, int* __restrict__ bucket_base)
{
    __shared__ int tmp[256];
    const int t = threadIdx.x;
    int v = (t < NBUCK) ? binctr[t] : 0;
    tmp[t] = v;
    __syncthreads();
    #pragma unroll
    for (int off = 1; off < 256; off <<= 1) {
        int u = (t >= off) ? tmp[t - off] : 0;
        __syncthreads();
        tmp[t] += u;
        __syncthreads();
    }
    if (t < NBUCK) bucket_base[t] = tmp[t] - v;
}

// One block per bucket: counting-sort its 256 dst nodes in LDS, write
// contiguous csr_src slice + row_start for its nodes.
__global__ __launch_bounds__(1024) void k_sort(
    const int* __restrict__ stg,
    const int* __restrict__ binctr, const int* __restrict__ bucket_base,
    int* __restrict__ row_start, int* __restrict__ csr_src)
{
    __shared__ int cnt[256];
    __shared__ int off[256];
    const int b = blockIdx.x, t = threadIdx.x;
    const int n = binctr[b];
    const int sbase = b * CAP;
    const int obase = bucket_base[b];

    if (t < 256) cnt[t] = 0;
    __syncthreads();

    int mv[5], mk[5], mr[5];
    int c = 0;
    for (int i = t; i < n; i += 1024) {
        int v = stg[sbase + i];
        int k = v >> 16;                 // dst & 255
        mv[c] = v & 0xFFFF;              // src
        mk[c] = k;
        mr[c] = atomicAdd(&cnt[k], 1);
        ++c;
    }
    __syncthreads();

    if (t < 256) off[t] = cnt[t];
    __syncthreads();
    #pragma unroll
    for (int o = 1; o < 256; o <<= 1) {
        int u = (t < 256 && t >= o) ? off[t - o] : 0;
        __syncthreads();
        if (t < 256) off[t] += u;
        __syncthreads();
    }
    // off = inclusive scan; exclusive prefix = off[k] - cnt[k]

    if (t < 256) {
        int node = b * 256 + t;
        if (node < N_NODES) row_start[node] = obase + off[t] - cnt[t];
    }
    if (b == NBUCK - 1 && t == 0) row_start[N_NODES] = N_EDGES;

    for (int i = 0; i < c; ++i)
        csr_src[obase + off[mk[i]] - cnt[mk[i]] + mr[i]] = mv[i];
}

// ---------------------------------------------------------------------------
// GEMM1: h1 = x @ W1  (50000x128 @ 128x64) -> fp16 rows; fused ls1/ld1 (fp32).
__global__ __launch_bounds__(256) void k_gemm1(
    const float* __restrict__ x, const float* __restrict__ W1,
    const float* __restrict__ a_src, const float* __restrict__ a_dst,
    _Float16* __restrict__ h1h, float* __restrict__ ls, float* __restrict__ ld)
{
    __shared__ float As[64][128];   // 32 KB
    __shared__ float Bs[128][64];   // 32 KB
    const int tid = threadIdx.x;
    const int m0 = blockIdx.x * 64;

    {   // W1 (128x64 = 2048 float4) -> Bs
        const float4* Wv = (const float4*)W1;
        float4* Bv = (float4*)&Bs[0][0];
        #pragma unroll
        for (int i = 0; i < 8; ++i) Bv[tid + i * 256] = Wv[tid + i * 256];
    }
    {   // x tile (64x128) -> As, coalesced float4, zero-pad past N
        const float4* Xv = (const float4*)x;
        #pragma unroll
        for (int i = 0; i < 8; ++i) {
            int idx = tid + i * 256;
            int r = idx >> 5, kq = idx & 31;        // 32 float4 per row
            float4 v = make_float4(0.f, 0.f, 0.f, 0.f);
            if (m0 + r < N_NODES) v = Xv[(size_t)(m0 + r) * 32 + kq];
            ((float4*)&As[r][0])[kq] = v;
        }
    }
    __syncthreads();

    const int tx = tid & 15, ty = tid >> 4;
    const int c0 = tx * 4, r0 = ty * 4;
    float acc[4][4] = {};
    for (int k = 0; k < 128; k += 4) {
        float a_s[4][4];
        #pragma unroll
        for (int i = 0; i < 4; ++i) {
            float4 av = *(const float4*)&As[r0 + i][k];
            a_s[i][0] = av.x; a_s[i][1] = av.y; a_s[i][2] = av.z; a_s[i][3] = av.w;
        }
        #pragma unroll
        for (int kk = 0; kk < 4; ++kk) {
            float4 b = *(const float4*)&Bs[k + kk][c0];
            #pragma unroll
            for (int i = 0; i < 4; ++i) {
                acc[i][0] += a_s[i][kk] * b.x;
                acc[i][1] += a_s[i][kk] * b.y;
                acc[i][2] += a_s[i][kk] * b.z;
                acc[i][3] += a_s[i][kk] * b.w;
            }
        }
    }

    float as4[4], ad4[4];
    #pragma unroll
    for (int j = 0; j < 4; ++j) { as4[j] = a_src[c0 + j]; ad4[j] = a_dst[c0 + j]; }

    #pragma unroll
    for (int i = 0; i < 4; ++i) {
        int row = m0 + r0 + i;
        float pls = acc[i][0]*as4[0] + acc[i][1]*as4[1] + acc[i][2]*as4[2] + acc[i][3]*as4[3];
        float pld = acc[i][0]*ad4[0] + acc[i][1]*ad4[1] + acc[i][2]*ad4[2] + acc[i][3]*ad4[3];
        #pragma unroll
        for (int off = 1; off < 16; off <<= 1) {
            pls += __shfl_xor(pls, off, 64);
            pld += __shfl_xor(pld, off, 64);
        }
        if (row < N_NODES) {
            half4 hv;
            hv.x = (_Float16)acc[i][0]; hv.y = (_Float16)acc[i][1];
            hv.z = (_Float16)acc[i][2]; hv.w = (_Float16)acc[i][3];
            ((half4*)&h1h[(size_t)row * 64])[tx] = hv;
            if (tx == 0) { ls[row] = pls; ld[row] = pld; }
        }
    }
}

// ---------------------------------------------------------------------------
// Aggregate layer 1 (C=64): one wave per dst node.
// Lane = (eslot = lane>>4, c4 = lane&15): 16 lanes gather a row as half4
// (8 B each, 128 B/row), 4 slots process 4 different edges concurrently.
__global__ __launch_bounds__(256) void k_agg1(
    const int* __restrict__ csr_src, const int* __restrict__ row_start,
    const float* __restrict__ ls, const float* __restrict__ ld,
    const _Float16* __restrict__ h1h, const float* __restrict__ b1,
    float* __restrict__ acc1)
{
    const int node = blockIdx.x * 4 + (threadIdx.x >> 6);  // 12500*4 == N_NODES
    const int lane = threadIdx.x & 63;
    const int c4 = lane & 15, eslot = lane >> 4;
    const int beg = row_start[node], end = row_start[node + 1];
    const float ldv = ld[node];
    const half4* H = (const half4*)h1h;

    float4 acc = make_float4(0.f, 0.f, 0.f, 0.f);
    float sw = 0.f;
    for (int base = beg; base < end; base += 64) {
        const int cnt = min(64, end - base);
        int s = 0;
        float w = 0.f;
        if (lane < cnt) {
            s = csr_src[base + lane];              // coalesced
            float l = ls[s] + ldv;                 // one exp per EDGE
            l = l > 0.f ? l : SLOPE * l;
            w = __expf(l);
        }
        float wsum = w;                            // denominator via butterfly
        #pragma unroll
        for (int off = 1; off < 64; off <<= 1) wsum += __shfl_xor(wsum, off, 64);
        sw += wsum;

        int j = 0;                                 // 8 edges per iter (2/slot)
        for (; j + 8 <= cnt; j += 8) {
            int   s0 = __shfl(s, j + eslot, 64);
            int   s1 = __shfl(s, j + 4 + eslot, 64);
            float w0 = __shfl(w, j + eslot, 64);
            float w1 = __shfl(w, j + 4 + eslot, 64);
            half4 g0 = H[(size_t)s0 * 16 + c4];
            half4 g1 = H[(size_t)s1 * 16 + c4];
            acc.x += w0 * (float)g0.x; acc.y += w0 * (float)g0.y;
            acc.z += w0 * (float)g0.z; acc.w += w0 * (float)g0.w;
            acc.x += w1 * (float)g1.x; acc.y += w1 * (float)g1.y;
            acc.z += w1 * (float)g1.z; acc.w += w1 * (float)g1.w;
        }
        for (; j < cnt; j += 4) {                  // tail: invalid slots have w=0
            int   sj = __shfl(s, j + eslot, 64);
            float wj = __shfl(w, j + eslot, 64);
            half4 g = H[(size_t)sj * 16 + c4];
            acc.x += wj * (float)g.x; acc.y += wj * (float)g.y;
            acc.z += wj * (float)g.z; acc.w += wj * (float)g.w;
        }
    }
    // reduce across the 4 edge slots (xor bits 4,5)
    #pragma unroll
    for (int off = 16; off < 64; off <<= 1) {
        acc.x += __shfl_xor(acc.x, off, 64);
        acc.y += __shfl_xor(acc.y, off, 64);
        acc.z += __shfl_xor(acc.z, off, 64);
        acc.w += __shfl_xor(acc.w, off, 64);
    }
    if (eslot == 0) {
        float inv = sw > 0.f ? 1.f / sw : 0.f;
        float4 bb = ((const float4*)b1)[c4];
        ((float4*)&acc1[(size_t)node * 64])[c4] =
            make_float4(acc.x * inv + bb.x, acc.y * inv + bb.y,
                        acc.z * inv + bb.z, acc.w * inv + bb.w);
    }
}

// ---------------------------------------------------------------------------
// Epilogue layer1 + GEMM2: h2 = relu(acc1) @ W2 -> fp16 rows; fused ls2/ld2.
__global__ __launch_bounds__(256) void k_epi1(
    const float* __restrict__ acc1, const float* __restrict__ W2,
    const float* __restrict__ a_src2, const float* __restrict__ a_dst2,
    _Float16* __restrict__ h2h, float* __restrict__ ls2, float* __restrict__ ld2)
{
    __shared__ float Hs[64][68];
    __shared__ float W2s[64][32];
    const int tid = threadIdx.x;
    const int n0 = blockIdx.x * 64;

    {   // W2 (64x32 = 512 float4) -> LDS
        const float4* Wv = (const float4*)W2;
        float4* Ws = (float4*)&W2s[0][0];
        Ws[tid] = Wv[tid];
        Ws[tid + 256] = Wv[tid + 256];
    }
    {   // relu(acc1 rows) -> Hs, coalesced
        const float4* Av = (const float4*)acc1;
        #pragma unroll
        for (int i = 0; i < 4; ++i) {
            int idx = tid + i * 256;
            int r = idx >> 4, kq = idx & 15;
            float4 v = make_float4(0.f, 0.f, 0.f, 0.f);
            if (n0 + r < N_NODES) {
                v = Av[(size_t)(n0 + r) * 16 + kq];
                v.x = fmaxf(v.x, 0.f); v.y = fmaxf(v.y, 0.f);
                v.z = fmaxf(v.z, 0.f); v.w = fmaxf(v.w, 0.f);
            }
            ((float4*)&Hs[r][0])[kq] = v;
        }
    }
    __syncthreads();

    const int nl = tid >> 2, cg = tid & 3, c0 = cg * 8;
    float acc[8] = {};
    for (int k4 = 0; k4 < 16; ++k4) {
        float4 hv4 = *(const float4*)&Hs[nl][k4 * 4];
        #pragma unroll
        for (int kk = 0; kk < 4; ++kk) {
            float hv = kk == 0 ? hv4.x : kk == 1 ? hv4.y : kk == 2 ? hv4.z : hv4.w;
            int k = k4 * 4 + kk;
            float4 w0 = *(const float4*)&W2s[k][c0];
            float4 w1 = *(const float4*)&W2s[k][c0 + 4];
            acc[0] += hv * w0.x; acc[1] += hv * w0.y;
            acc[2] += hv * w0.z; acc[3] += hv * w0.w;
            acc[4] += hv * w1.x; acc[5] += hv * w1.y;
            acc[6] += hv * w1.z; acc[7] += hv * w1.w;
        }
    }

    float pls = 0.f, pld = 0.f;
    #pragma unroll
    for (int j = 0; j < 8; ++j) {
        pls += acc[j] * a_src2[c0 + j];
        pld += acc[j] * a_dst2[c0 + j];
    }
    pls += __shfl_xor(pls, 1, 64); pls += __shfl_xor(pls, 2, 64);
    pld += __shfl_xor(pld, 1, 64); pld += __shfl_xor(pld, 2, 64);

    int node = n0 + nl;
    if (node < N_NODES) {
        half4 lo, hi;
        lo.x = (_Float16)acc[0]; lo.y = (_Float16)acc[1];
        lo.z = (_Float16)acc[2]; lo.w = (_Float16)acc[3];
        hi.x = (_Float16)acc[4]; hi.y = (_Float16)acc[5];
        hi.z = (_Float16)acc[6]; hi.w = (_Float16)acc[7];
        ((half4*)&h2h[(size_t)node * 32])[cg * 2]     = lo;
        ((half4*)&h2h[(size_t)node * 32])[cg * 2 + 1] = hi;
        if (cg == 0) { ls2[node] = pls; ld2[node] = pld; }
    }
}

// ---------------------------------------------------------------------------
// Aggregate layer 2 (C=32): one 32-lane group per dst node.
// c4 = grp&7 (8 half4 channel groups, 64 B/row), eslot = grp>>3 (4 slots).
__global__ __launch_bounds__(256) void k_agg2(
    const int* __restrict__ csr_src, const int* __restrict__ row_start,
    const float* __restrict__ ls, const float* __restrict__ ld,
    const _Float16* __restrict__ h2h, const float* __restrict__ b2,
    float* __restrict__ out)
{
    const int idx = blockIdx.x * 256 + threadIdx.x;   // 6250*256 == N*32
    const int node = idx >> 5;
    const int grp = idx & 31;
    const int c4 = grp & 7, eslot = grp >> 3;
    const int beg = row_start[node], end = row_start[node + 1];
    const float ldv = ld[node];
    const half4* H = (const half4*)h2h;

    float4 acc = make_float4(0.f, 0.f, 0.f, 0.f);
    float sw = 0.f;
    for (int base = beg; base < end; base += 32) {
        const int cnt = min(32, end - base);
        int s = 0;
        float w = 0.f;
        if (grp < cnt) {
            s = csr_src[base + grp];
            float l = ls[s] + ldv;
            l = l > 0.f ? l : SLOPE * l;
            w = __expf(l);
        }
        float wsum = w;
        #pragma unroll
        for (int off = 1; off < 32; off <<= 1) wsum += __shfl_xor(wsum, off, 32);
        sw += wsum;

        int j = 0;
        for (; j + 8 <= cnt; j += 8) {
            int   s0 = __shfl(s, j + eslot, 32);
            int   s1 = __shfl(s, j + 4 + eslot, 32);
            float w0 = __shfl(w, j + eslot, 32);
            float w1 = __shfl(w, j + 4 + eslot, 32);
            half4 g0 = H[(size_t)s0 * 8 + c4];
            half4 g1 = H[(size_t)s1 * 8 + c4];
            acc.x += w0 * (float)g0.x; acc.y += w0 * (float)g0.y;
            acc.z += w0 * (float)g0.z; acc.w += w0 * (float)g0.w;
            acc.x += w1 * (float)g1.x; acc.y += w1 * (float)g1.y;
            acc.z += w1 * (float)g1.z; acc.w += w1 * (float)g1.w;
        }
        for (; j < cnt; j += 4) {
            int   sj = __shfl(s, j + eslot, 32);
            float wj = __shfl(w, j + eslot, 32);
            half4 g = H[(size_t)sj * 8 + c4];
            acc.x += wj * (float)g.x; acc.y += wj * (float)g.y;
            acc.z += wj * (float)g.z; acc.w += wj * (float)g.w;
        }
    }
    // reduce across the 4 edge slots (xor bits 3,4 of grp)
    #pragma unroll
    for (int off = 8; off < 32; off <<= 1) {
        acc.x += __shfl_xor(acc.x, off, 32);
        acc.y += __shfl_xor(acc.y, off, 32);
        acc.z += __shfl_xor(acc.z, off, 32);
        acc.w += __shfl_xor(acc.w, off, 32);
    }
    if (eslot == 0) {
        float inv = sw > 0.f ? 1.f / sw : 0.f;
        float4 bb = ((const float4*)b2)[c4];
        ((float4*)&out[(size_t)node * 32])[c4] =
            make_float4(acc.x * inv + bb.x, acc.y * inv + bb.y,
                        acc.z * inv + bb.z, acc.w * inv + bb.w);
    }
}

// ---------------------------------------------------------------------------
extern "C" void kernel_launch(void* const* d_in, const int* in_sizes, int n_in,
                              void* d_out, int out_size, void* d_ws, size_t ws_size,
                              hipStream_t stream)
{
    const float* x      = (const float*)d_in[0];
    const int*   ei     = (const int*)  d_in[1];
    const float* W1     = (const float*)d_in[2];
    const float* a_src1 = (const float*)d_in[3];
    const float* a_dst1 = (const float*)d_in[4];
    const float* b1     = (const float*)d_in[5];
    const float* W2     = (const float*)d_in[6];
    const float* a_src2 = (const float*)d_in[7];
    const float* a_dst2 = (const float*)d_in[8];
    const float* b2     = (const float*)d_in[9];
    const int* src = ei;
    const int* dst = ei + N_EDGES;
    float* out = (float*)d_out;

    // workspace layout (4B words), total ~5.75M words = 23 MB.
    // h1h (fp16, 1.6M words) holds 50000x64 halfs; stg (903,168 i) aliases it
    // (CSR build fully precedes k_gemm1 on the stream). h2h aliases h1h too
    // (50000x32 halfs = 0.8M words).
    float* ws   = (float*)d_ws;
    _Float16* h1h = (_Float16*)ws;           // words 0 .. 1,600,000
    float* acc1 = ws + 1600000;              // 3,200,000 f
    float* ls1  = ws + 4800000;              // 50,000 f
    float* ld1  = ws + 4850000;              // 50,000 f
    int* row_start   = (int*)(ws + 4900000); // 50,001 i (pad to 50,016)
    int* csr_src     = (int*)(ws + 4950016); // 800,000 i
    int* binctr      = (int*)(ws + 5750016); // 196 i (pad 256)
    int* bucket_base = (int*)(ws + 5750272); // 196 i (pad 256)
    int* stg = (int*)ws;                     // aliases h1h region
    _Float16* h2h = h1h;
    float* ls2 = ls1;
    float* ld2 = ld1;

    // CSR build (dst-sorted, reused by both layers)
    k_zerobins<<<1,   256,  0, stream>>>(binctr);
    k_bin     <<<196, 1024, 0, stream>>>(src, dst, binctr, stg);
    k_btot    <<<1,   256,  0, stream>>>(binctr, bucket_base);
    k_sort    <<<NBUCK, 1024, 0, stream>>>(stg, binctr, bucket_base,
                                           row_start, csr_src);

    // layer 1
    k_gemm1<<<782,   256, 0, stream>>>(x, W1, a_src1, a_dst1, h1h, ls1, ld1);
    k_agg1 <<<12500, 256, 0, stream>>>(csr_src, row_start, ls1, ld1, h1h, b1, acc1);

    // layer 2
    k_epi1 <<<782,  256, 0, stream>>>(acc1, W2, a_src2, a_dst2, h2h, ls2, ld2);
    k_agg2 <<<6250, 256, 0, stream>>>(csr_src, row_start, ls2, ld2, h2h, b2, out);
}

// Round 10
// 169.408 us; speedup vs baseline: 1.1391x; 1.0716x over previous
//
#include <hip/hip_runtime.h>
#include <hip/hip_fp16.h>

// 2-layer single-head GATConv, fp32 in/out, MI355X.
// N=50000 nodes, E=800000 edges, IN=128, HID=64, OUT=32.
//
// Round 9 -> 10 (round 9 was neutral: bin isn't occupancy-bound):
//  (a) k_bin and k_gemm1 are data-independent -> merged into one k_pre
//      launch (blocks 0..195 = bin @ 256thr x 16 edges, same 4096
//      edges/block write density; blocks 196..977 = gemm1 unchanged).
//      stg gets its own region (no longer aliases h1h - concurrent now).
//  (b) k_btot folded into k_sort (each block scans the 196 counts in LDS).
//  (c) csr_src stored as ushort (src < 2^16): halves edge-list bytes in
//      sort-write and both agg-kernel reads.

#define N_NODES 50000
#define N_EDGES 800000
#define SLOPE 0.2f
#define NBUCK 196           // ceil(50000/256) buckets of 256 dst nodes
#define CAP 4608            // staging capacity per bucket (mean ~4082)
#define BIN_BLOCKS 196      // k_pre blocks doing edge binning (4096 edges each)
#define GEMM_BLOCKS 782     // k_pre blocks doing gemm1 (64 rows each)

typedef _Float16 half4 __attribute__((ext_vector_type(4)));

// ---------------------------------------------------------------------------
__global__ __launch_bounds__(256) void k_zerobins(int* __restrict__ binctr)
{
    if (threadIdx.x < NBUCK) binctr[threadIdx.x] = 0;
}

// ---------------------------------------------------------------------------
// Fused: blocks 0..195 stage edges into dst-buckets; blocks 196..977 compute
// GEMM1 h1 = x @ W1 -> fp16 rows + fused ls1/ld1 scores. Independent work.
__global__ __launch_bounds__(256) void k_pre(
    const int* __restrict__ src, const int* __restrict__ dst,
    int* __restrict__ binctr, int* __restrict__ stg,
    const float* __restrict__ x, const float* __restrict__ W1,
    const float* __restrict__ a_src, const float* __restrict__ a_dst,
    _Float16* __restrict__ h1h, float* __restrict__ ls, float* __restrict__ ld)
{
    __shared__ float As[64][128];   // 32 KB (gemm branch)
    __shared__ float Bs[128][64];   // 32 KB (gemm branch)
    __shared__ int hist[NBUCK];     // bin branch
    __shared__ int gb[NBUCK];
    const int tid = threadIdx.x;

    if (blockIdx.x < BIN_BLOCKS) {
        // ----- bin: 4096 edges/block, 16 per thread -----
        if (tid < NBUCK) hist[tid] = 0;
        __syncthreads();

        const int base = blockIdx.x * 4096;
        int ms[16], md[16], mr[16];
        #pragma unroll
        for (int k = 0; k < 16; ++k) {
            int e = base + tid + k * 256;          // base+4096 <= 802816 OK (pad below)
            int s = 0, d = 0;
            if (e < N_EDGES) { s = src[e]; d = dst[e]; }
            ms[k] = s; md[k] = d;
            mr[k] = (e < N_EDGES) ? atomicAdd(&hist[d >> 8], 1) : -1;
        }
        __syncthreads();
        if (tid < NBUCK) gb[tid] = atomicAdd(&binctr[tid], hist[tid]);
        __syncthreads();
        #pragma unroll
        for (int k = 0; k < 16; ++k) {
            if (mr[k] >= 0) {
                int b = md[k] >> 8;
                stg[b * CAP + gb[b] + mr[k]] = ms[k] | ((md[k] & 255) << 16);
            }
        }
        return;
    }

    // ----- gemm1: 64-row tile -----
    const int m0 = (blockIdx.x - BIN_BLOCKS) * 64;

    {   // W1 (128x64 = 2048 float4) -> Bs
        const float4* Wv = (const float4*)W1;
        float4* Bv = (float4*)&Bs[0][0];
        #pragma unroll
        for (int i = 0; i < 8; ++i) Bv[tid + i * 256] = Wv[tid + i * 256];
    }
    {   // x tile (64x128) -> As, coalesced float4, zero-pad past N
        const float4* Xv = (const float4*)x;
        #pragma unroll
        for (int i = 0; i < 8; ++i) {
            int idx = tid + i * 256;
            int r = idx >> 5, kq = idx & 31;        // 32 float4 per row
            float4 v = make_float4(0.f, 0.f, 0.f, 0.f);
            if (m0 + r < N_NODES) v = Xv[(size_t)(m0 + r) * 32 + kq];
            ((float4*)&As[r][0])[kq] = v;
        }
    }
    __syncthreads();

    const int tx = tid & 15, ty = tid >> 4;
    const int c0 = tx * 4, r0 = ty * 4;
    float acc[4][4] = {};
    for (int k = 0; k < 128; k += 4) {
        float a_s[4][4];
        #pragma unroll
        for (int i = 0; i < 4; ++i) {
            float4 av = *(const float4*)&As[r0 + i][k];
            a_s[i][0] = av.x; a_s[i][1] = av.y; a_s[i][2] = av.z; a_s[i][3] = av.w;
        }
        #pragma unroll
        for (int kk = 0; kk < 4; ++kk) {
            float4 b = *(const float4*)&Bs[k + kk][c0];
            #pragma unroll
            for (int i = 0; i < 4; ++i) {
                acc[i][0] += a_s[i][kk] * b.x;
                acc[i][1] += a_s[i][kk] * b.y;
                acc[i][2] += a_s[i][kk] * b.z;
                acc[i][3] += a_s[i][kk] * b.w;
            }
        }
    }

    float as4[4], ad4[4];
    #pragma unroll
    for (int j = 0; j < 4; ++j) { as4[j] = a_src[c0 + j]; ad4[j] = a_dst[c0 + j]; }

    #pragma unroll
    for (int i = 0; i < 4; ++i) {
        int row = m0 + r0 + i;
        float pls = acc[i][0]*as4[0] + acc[i][1]*as4[1] + acc[i][2]*as4[2] + acc[i][3]*as4[3];
        float pld = acc[i][0]*ad4[0] + acc[i][1]*ad4[1] + acc[i][2]*ad4[2] + acc[i][3]*ad4[3];
        #pragma unroll
        for (int off = 1; off < 16; off <<= 1) {
            pls += __shfl_xor(pls, off, 64);
            pld += __shfl_xor(pld, off, 64);
        }
        if (row < N_NODES) {
            half4 hv;
            hv.x = (_Float16)acc[i][0]; hv.y = (_Float16)acc[i][1];
            hv.z = (_Float16)acc[i][2]; hv.w = (_Float16)acc[i][3];
            ((half4*)&h1h[(size_t)row * 64])[tx] = hv;
            if (tx == 0) { ls[row] = pls; ld[row] = pld; }
        }
    }
}

// ---------------------------------------------------------------------------
// One block per bucket: compute bucket base (in-block scan of binctr),
// counting-sort 256 dst nodes in LDS, write contiguous ushort csr slice +
// row_start.
__global__ __launch_bounds__(1024) void k_sort(
    const int* __restrict__ stg, const int* __restrict__ binctr,
    int* __restrict__ row_start, unsigned short* __restrict__ csr_src)
{
    __shared__ int cnt[256];
    __shared__ int off[256];
    __shared__ int sc[256];
    const int b = blockIdx.x, t = threadIdx.x;
    const int n = binctr[b];
    const int sbase = b * CAP;

    // bucket base = exclusive prefix of binctr over buckets (replaces k_btot)
    if (t < 256) { sc[t] = (t < NBUCK) ? binctr[t] : 0; cnt[t] = 0; }
    __syncthreads();
    #pragma unroll
    for (int o = 1; o < 256; o <<= 1) {
        int u = (t < 256 && t >= o) ? sc[t - o] : 0;
        __syncthreads();
        if (t < 256) sc[t] += u;
        __syncthreads();
    }
    const int obase = sc[b] - n;     // exclusive prefix for this bucket

    int mv[5], mk[5], mr[5];
    int c = 0;
    for (int i = t; i < n; i += 1024) {
        int v = stg[sbase + i];
        int k = v >> 16;                 // dst & 255
        mv[c] = v & 0xFFFF;              // src
        mk[c] = k;
        mr[c] = atomicAdd(&cnt[k], 1);
        ++c;
    }
    __syncthreads();

    if (t < 256) off[t] = cnt[t];
    __syncthreads();
    #pragma unroll
    for (int o = 1; o < 256; o <<= 1) {
        int u = (t < 256 && t >= o) ? off[t - o] : 0;
        __syncthreads();
        if (t < 256) off[t] += u;
        __syncthreads();
    }
    // off = inclusive scan; exclusive prefix = off[k] - cnt[k]

    if (t < 256) {
        int node = b * 256 + t;
        if (node < N_NODES) row_start[node] = obase + off[t] - cnt[t];
    }
    if (b == NBUCK - 1 && t == 0) row_start[N_NODES] = N_EDGES;

    for (int i = 0; i < c; ++i)
        csr_src[obase + off[mk[i]] - cnt[mk[i]] + mr[i]] = (unsigned short)mv[i];
}

// ---------------------------------------------------------------------------
// Aggregate layer 1 (C=64): one wave per dst node.
// Lane = (eslot = lane>>4, c4 = lane&15): 16 lanes gather a row as half4,
// 4 slots process 4 different edges concurrently.
__global__ __launch_bounds__(256) void k_agg1(
    const unsigned short* __restrict__ csr_src, const int* __restrict__ row_start,
    const float* __restrict__ ls, const float* __restrict__ ld,
    const _Float16* __restrict__ h1h, const float* __restrict__ b1,
    float* __restrict__ acc1)
{
    const int node = blockIdx.x * 4 + (threadIdx.x >> 6);  // 12500*4 == N_NODES
    const int lane = threadIdx.x & 63;
    const int c4 = lane & 15, eslot = lane >> 4;
    const int beg = row_start[node], end = row_start[node + 1];
    const float ldv = ld[node];
    const half4* H = (const half4*)h1h;

    float4 acc = make_float4(0.f, 0.f, 0.f, 0.f);
    float sw = 0.f;
    for (int base = beg; base < end; base += 64) {
        const int cnt = min(64, end - base);
        int s = 0;
        float w = 0.f;
        if (lane < cnt) {
            s = csr_src[base + lane];              // coalesced 2B/lane
            float l = ls[s] + ldv;                 // one exp per EDGE
            l = l > 0.f ? l : SLOPE * l;
            w = __expf(l);
        }
        float wsum = w;                            // denominator via butterfly
        #pragma unroll
        for (int off = 1; off < 64; off <<= 1) wsum += __shfl_xor(wsum, off, 64);
        sw += wsum;

        int j = 0;                                 // 8 edges per iter (2/slot)
        for (; j + 8 <= cnt; j += 8) {
            int   s0 = __shfl(s, j + eslot, 64);
            int   s1 = __shfl(s, j + 4 + eslot, 64);
            float w0 = __shfl(w, j + eslot, 64);
            float w1 = __shfl(w, j + 4 + eslot, 64);
            half4 g0 = H[(size_t)s0 * 16 + c4];
            half4 g1 = H[(size_t)s1 * 16 + c4];
            acc.x += w0 * (float)g0.x; acc.y += w0 * (float)g0.y;
            acc.z += w0 * (float)g0.z; acc.w += w0 * (float)g0.w;
            acc.x += w1 * (float)g1.x; acc.y += w1 * (float)g1.y;
            acc.z += w1 * (float)g1.z; acc.w += w1 * (float)g1.w;
        }
        for (; j < cnt; j += 4) {                  // tail: invalid slots have w=0
            int   sj = __shfl(s, j + eslot, 64);
            float wj = __shfl(w, j + eslot, 64);
            half4 g = H[(size_t)sj * 16 + c4];
            acc.x += wj * (float)g.x; acc.y += wj * (float)g.y;
            acc.z += wj * (float)g.z; acc.w += wj * (float)g.w;
        }
    }
    // reduce across the 4 edge slots (xor bits 4,5)
    #pragma unroll
    for (int off = 16; off < 64; off <<= 1) {
        acc.x += __shfl_xor(acc.x, off, 64);
        acc.y += __shfl_xor(acc.y, off, 64);
        acc.z += __shfl_xor(acc.z, off, 64);
        acc.w += __shfl_xor(acc.w, off, 64);
    }
    if (eslot == 0) {
        float inv = sw > 0.f ? 1.f / sw : 0.f;
        float4 bb = ((const float4*)b1)[c4];
        ((float4*)&acc1[(size_t)node * 64])[c4] =
            make_float4(acc.x * inv + bb.x, acc.y * inv + bb.y,
                        acc.z * inv + bb.z, acc.w * inv + bb.w);
    }
}

// ---------------------------------------------------------------------------
// Epilogue layer1 + GEMM2: h2 = relu(acc1) @ W2 -> fp16 rows; fused ls2/ld2.
__global__ __launch_bounds__(256) void k_epi1(
    const float* __restrict__ acc1, const float* __restrict__ W2,
    const float* __restrict__ a_src2, const float* __restrict__ a_dst2,
    _Float16* __restrict__ h2h, float* __restrict__ ls2, float* __restrict__ ld2)
{
    __shared__ float Hs[64][68];
    __shared__ float W2s[64][32];
    const int tid = threadIdx.x;
    const int n0 = blockIdx.x * 64;

    {   // W2 (64x32 = 512 float4) -> LDS
        const float4* Wv = (const float4*)W2;
        float4* Ws = (float4*)&W2s[0][0];
        Ws[tid] = Wv[tid];
        Ws[tid + 256] = Wv[tid + 256];
    }
    {   // relu(acc1 rows) -> Hs, coalesced
        const float4* Av = (const float4*)acc1;
        #pragma unroll
        for (int i = 0; i < 4; ++i) {
            int idx = tid + i * 256;
            int r = idx >> 4, kq = idx & 15;
            float4 v = make_float4(0.f, 0.f, 0.f, 0.f);
            if (n0 + r < N_NODES) {
                v = Av[(size_t)(n0 + r) * 16 + kq];
                v.x = fmaxf(v.x, 0.f); v.y = fmaxf(v.y, 0.f);
                v.z = fmaxf(v.z, 0.f); v.w = fmaxf(v.w, 0.f);
            }
            ((float4*)&Hs[r][0])[kq] = v;
        }
    }
    __syncthreads();

    const int nl = tid >> 2, cg = tid & 3, c0 = cg * 8;
    float acc[8] = {};
    for (int k4 = 0; k4 < 16; ++k4) {
        float4 hv4 = *(const float4*)&Hs[nl][k4 * 4];
        #pragma unroll
        for (int kk = 0; kk < 4; ++kk) {
            float hv = kk == 0 ? hv4.x : kk == 1 ? hv4.y : kk == 2 ? hv4.z : hv4.w;
            int k = k4 * 4 + kk;
            float4 w0 = *(const float4*)&W2s[k][c0];
            float4 w1 = *(const float4*)&W2s[k][c0 + 4];
            acc[0] += hv * w0.x; acc[1] += hv * w0.y;
            acc[2] += hv * w0.z; acc[3] += hv * w0.w;
            acc[4] += hv * w1.x; acc[5] += hv * w1.y;
            acc[6] += hv * w1.z; acc[7] += hv * w1.w;
        }
    }

    float pls = 0.f, pld = 0.f;
    #pragma unroll
    for (int j = 0; j < 8; ++j) {
        pls += acc[j] * a_src2[c0 + j];
        pld += acc[j] * a_dst2[c0 + j];
    }
    pls += __shfl_xor(pls, 1, 64); pls += __shfl_xor(pls, 2, 64);
    pld += __shfl_xor(pld, 1, 64); pld += __shfl_xor(pld, 2, 64);

    int node = n0 + nl;
    if (node < N_NODES) {
        half4 lo, hi;
        lo.x = (_Float16)acc[0]; lo.y = (_Float16)acc[1];
        lo.z = (_Float16)acc[2]; lo.w = (_Float16)acc[3];
        hi.x = (_Float16)acc[4]; hi.y = (_Float16)acc[5];
        hi.z = (_Float16)acc[6]; hi.w = (_Float16)acc[7];
        ((half4*)&h2h[(size_t)node * 32])[cg * 2]     = lo;
        ((half4*)&h2h[(size_t)node * 32])[cg * 2 + 1] = hi;
        if (cg == 0) { ls2[node] = pls; ld2[node] = pld; }
    }
}

// ---------------------------------------------------------------------------
// Aggregate layer 2 (C=32): one 32-lane group per dst node.
// c4 = grp&7 (8 half4 channel groups, 64 B/row), eslot = grp>>3 (4 slots).
__global__ __launch_bounds__(256) void k_agg2(
    const unsigned short* __restrict__ csr_src, const int* __restrict__ row_start,
    const float* __restrict__ ls, const float* __restrict__ ld,
    const _Float16* __restrict__ h2h, const float* __restrict__ b2,
    float* __restrict__ out)
{
    const int idx = blockIdx.x * 256 + threadIdx.x;   // 6250*256 == N*32
    const int node = idx >> 5;
    const int grp = idx & 31;
    const int c4 = grp & 7, eslot = grp >> 3;
    const int beg = row_start[node], end = row_start[node + 1];
    const float ldv = ld[node];
    const half4* H = (const half4*)h2h;

    float4 acc = make_float4(0.f, 0.f, 0.f, 0.f);
    float sw = 0.f;
    for (int base = beg; base < end; base += 32) {
        const int cnt = min(32, end - base);
        int s = 0;
        float w = 0.f;
        if (grp < cnt) {
            s = csr_src[base + grp];
            float l = ls[s] + ldv;
            l = l > 0.f ? l : SLOPE * l;
            w = __expf(l);
        }
        float wsum = w;
        #pragma unroll
        for (int off = 1; off < 32; off <<= 1) wsum += __shfl_xor(wsum, off, 32);
        sw += wsum;

        int j = 0;
        for (; j + 8 <= cnt; j += 8) {
            int   s0 = __shfl(s, j + eslot, 32);
            int   s1 = __shfl(s, j + 4 + eslot, 32);
            float w0 = __shfl(w, j + eslot, 32);
            float w1 = __shfl(w, j + 4 + eslot, 32);
            half4 g0 = H[(size_t)s0 * 8 + c4];
            half4 g1 = H[(size_t)s1 * 8 + c4];
            acc.x += w0 * (float)g0.x; acc.y += w0 * (float)g0.y;
            acc.z += w0 * (float)g0.z; acc.w += w0 * (float)g0.w;
            acc.x += w1 * (float)g1.x; acc.y += w1 * (float)g1.y;
            acc.z += w1 * (float)g1.z; acc.w += w1 * (float)g1.w;
        }
        for (; j < cnt; j += 4) {
            int   sj = __shfl(s, j + eslot, 32);
            float wj = __shfl(w, j + eslot, 32);
            half4 g = H[(size_t)sj * 8 + c4];
            acc.x += wj * (float)g.x; acc.y += wj * (float)g.y;
            acc.z += wj * (float)g.z; acc.w += wj * (float)g.w;
        }
    }
    // reduce across the 4 edge slots (xor bits 3,4 of grp)
    #pragma unroll
    for (int off = 8; off < 32; off <<= 1) {
        acc.x += __shfl_xor(acc.x, off, 32);
        acc.y += __shfl_xor(acc.y, off, 32);
        acc.z += __shfl_xor(acc.z, off, 32);
        acc.w += __shfl_xor(acc.w, off, 32);
    }
    if (eslot == 0) {
        float inv = sw > 0.f ? 1.f / sw : 0.f;
        float4 bb = ((const float4*)b2)[c4];
        ((float4*)&out[(size_t)node * 32])[c4] =
            make_float4(acc.x * inv + bb.x, acc.y * inv + bb.y,
                        acc.z * inv + bb.z, acc.w * inv + bb.w);
    }
}

// ---------------------------------------------------------------------------
extern "C" void kernel_launch(void* const* d_in, const int* in_sizes, int n_in,
                              void* d_out, int out_size, void* d_ws, size_t ws_size,
                              hipStream_t stream)
{
    const float* x      = (const float*)d_in[0];
    const int*   ei     = (const int*)  d_in[1];
    const float* W1     = (const float*)d_in[2];
    const float* a_src1 = (const float*)d_in[3];
    const float* a_dst1 = (const float*)d_in[4];
    const float* b1     = (const float*)d_in[5];
    const float* W2     = (const float*)d_in[6];
    const float* a_src2 = (const float*)d_in[7];
    const float* a_dst2 = (const float*)d_in[8];
    const float* b2     = (const float*)d_in[9];
    const int* src = ei;
    const int* dst = ei + N_EDGES;
    float* out = (float*)d_out;

    // workspace layout (4B words), total ~6.26M words = 25 MB.
    // stg has its OWN region now (bin runs concurrently with gemm1 writing
    // h1h). h2h aliases h1h; ls2/ld2 alias ls1/ld1 (epi1 runs after agg1
    // consumed all layer-1 data).
    float* ws   = (float*)d_ws;
    _Float16* h1h = (_Float16*)ws;                   // words 0..1,600,000
    float* acc1 = ws + 1600000;                      // 3,200,000 f
    float* ls1  = ws + 4800000;                      // 50,000 f
    float* ld1  = ws + 4850000;                      // 50,000 f
    int* row_start = (int*)(ws + 4900000);           // 50,001 i (pad 50,016)
    unsigned short* csr16 = (unsigned short*)(ws + 4950016); // 800,000 u16 (400,016 w)
    int* binctr = (int*)(ws + 5350032);              // 196 i (pad 256)
    int* stg    = (int*)(ws + 5350288);              // 196*4608 = 903,168 i
    _Float16* h2h = h1h;
    float* ls2 = ls1;
    float* ld2 = ld1;

    k_zerobins<<<1, 256, 0, stream>>>(binctr);
    // fused bin (blocks 0..195) + gemm1 (blocks 196..977)
    k_pre  <<<BIN_BLOCKS + GEMM_BLOCKS, 256, 0, stream>>>(
        src, dst, binctr, stg, x, W1, a_src1, a_dst1, h1h, ls1, ld1);
    k_sort <<<NBUCK, 1024, 0, stream>>>(stg, binctr, row_start, csr16);
    k_agg1 <<<12500, 256, 0, stream>>>(csr16, row_start, ls1, ld1, h1h, b1, acc1);
    k_epi1 <<<782,  256, 0, stream>>>(acc1, W2, a_src2, a_dst2, h2h, ls2, ld2);
    k_agg2 <<<6250, 256, 0, stream>>>(csr16, row_start, ls2, ld2, h2h, b2, out);
}